// Round 4
// baseline (503.645 us; speedup 1.0000x reference)
//
#include <hip/hip_runtime.h>
#include <hip/hip_bf16.h>
#include <math.h>

// Problem constants (b=4,h=8,t=8192,d=64, c=64 clusters, wsz=128)
#define NB 4
#define NH 8
#define TT 8192
#define DD 64
#define NC 64
#define WW 128
#define BHN 32            // NB*NH
#define SCALE 0.125f      // d^-0.5
#define INVCAP 24         // max tracked clusters per token

typedef __bf16 bf16x8 __attribute__((ext_vector_type(8)));
typedef float  f32x4  __attribute__((ext_vector_type(4)));
typedef unsigned long long u64;

#define MFMA(a, b, c) __builtin_amdgcn_mfma_f32_16x16x32_bf16((a), (b), (c), 0, 0, 0)

// monotone fixed-point key: dv in [-1,1] -> (dv+1)*2^62, clamped below 2^63
__device__ __forceinline__ u64 fixkey(double dv) {
    const double k = (dv + 1.0) * 4611686018427387904.0;
    return (u64)fmin(k, 9223371487098961920.0);
}

// ---------------------------------------------------------------------------
// Kernel 1: routing dists in fp64 -> fixed-point u64 keys (+ loss partials).
// means staged fp64 in LDS (uniform broadcast reads); 2 tokens per thread.
// ---------------------------------------------------------------------------
__global__ __launch_bounds__(256) void k_dists(
    const float* __restrict__ qk, const float* __restrict__ means,
    u64* __restrict__ keys, double* __restrict__ lossa)
{
    __shared__ double mS[NC * DD];     // 32 KB fp64 means
    __shared__ double mn2[NC];
    __shared__ double red[4];

    const int bh  = blockIdx.x;        // 0..31
    const int h   = bh & 7;
    const int tid = threadIdx.x;
    const int t0  = blockIdx.y * 512 + tid;     // token A; token B = t0+256

    const float* mp = means + h * (NC * DD);
    for (int i = tid; i < NC * DD; i += 256) mS[i] = (double)mp[i];
    __syncthreads();
    if (tid < NC) {
        double s = 0.0;
        for (int d = 0; d < DD; d++) { const double m = mS[tid * DD + d]; s = fma(m, m, s); }
        mn2[tid] = s;
    }
    __syncthreads();

    float rr[2][DD];
#pragma unroll
    for (int tok = 0; tok < 2; tok++) {
        const float* src = qk + ((size_t)bh * TT + t0 + tok * 256) * DD;
#pragma unroll
        for (int i = 0; i < DD / 4; i++) {
            float4 t4 = ((const float4*)src)[i];
            rr[tok][4*i+0] = t4.x; rr[tok][4*i+1] = t4.y;
            rr[tok][4*i+2] = t4.z; rr[tok][4*i+3] = t4.w;
        }
    }
    double ss[2], inv[2];
#pragma unroll
    for (int tok = 0; tok < 2; tok++) {
        double s = 0.0;
#pragma unroll
        for (int i = 0; i < DD; i++) s = fma((double)rr[tok][i], (double)rr[tok][i], s);
        ss[tok] = s;
        inv[tok] = 1.0 / fmax(sqrt(s), 1e-12);
    }

    double dmax[2] = {-1e300, -1e300}; int cbest[2] = {0, 0};
    u64* kb = keys + (size_t)bh * NC * TT;

    for (int c0 = 0; c0 < NC; c0 += 8) {
        double a[2][8];
#pragma unroll
        for (int tok = 0; tok < 2; tok++)
#pragma unroll
            for (int cc = 0; cc < 8; cc++) a[tok][cc] = 0.0;

#pragma unroll
        for (int d0 = 0; d0 < DD; d0 += 4) {
            const double ra0 = (double)rr[0][d0+0], ra1 = (double)rr[0][d0+1];
            const double ra2 = (double)rr[0][d0+2], ra3 = (double)rr[0][d0+3];
            const double rb0 = (double)rr[1][d0+0], rb1 = (double)rr[1][d0+1];
            const double rb2 = (double)rr[1][d0+2], rb3 = (double)rr[1][d0+3];
#pragma unroll
            for (int cc = 0; cc < 8; cc++) {
                const double2 m01 = *(const double2*)(mS + (c0 + cc) * DD + d0);
                const double2 m23 = *(const double2*)(mS + (c0 + cc) * DD + d0 + 2);
                a[0][cc] = fma(ra0, m01.x, a[0][cc]);
                a[0][cc] = fma(ra1, m01.y, a[0][cc]);
                a[0][cc] = fma(ra2, m23.x, a[0][cc]);
                a[0][cc] = fma(ra3, m23.y, a[0][cc]);
                a[1][cc] = fma(rb0, m01.x, a[1][cc]);
                a[1][cc] = fma(rb1, m01.y, a[1][cc]);
                a[1][cc] = fma(rb2, m23.x, a[1][cc]);
                a[1][cc] = fma(rb3, m23.y, a[1][cc]);
            }
        }
#pragma unroll
        for (int tok = 0; tok < 2; tok++)
#pragma unroll
            for (int cc = 0; cc < 8; cc++) {
                const double dv = a[tok][cc] * inv[tok];
                kb[(size_t)(c0 + cc) * TT + t0 + tok * 256] = fixkey(dv);
                if (dv > dmax[tok]) { dmax[tok] = dv; cbest[tok] = c0 + cc; }
            }
    }

    double lt = fma(ss[0], inv[0] * inv[0], mn2[cbest[0]] - 2.0 * dmax[0])
              + fma(ss[1], inv[1] * inv[1], mn2[cbest[1]] - 2.0 * dmax[1]);
#pragma unroll
    for (int o = 32; o; o >>= 1) lt += __shfl_xor(lt, o);
    if ((tid & 63) == 0) red[tid >> 6] = lt;
    __syncthreads();
    if (tid == 0) atomicAdd(lossa, red[0] + red[1] + red[2] + red[3]);
}

// ---------------------------------------------------------------------------
// Kernel 2: top-128 per (bh,c), 8-bit radix select on uniform fixed-point
// keys (256 bins x 4 wave-copies). Emits ascending-sorted indices + inverse
// map (cnt, inv) for k_out.
// ---------------------------------------------------------------------------
__global__ __launch_bounds__(256) void k_topk(
    const u64* __restrict__ keys, int* __restrict__ indices,
    unsigned int* __restrict__ cnt, unsigned short* __restrict__ inv)
{
    __shared__ unsigned int hist[4][256];    // 4 KB
    __shared__ int wsum[8];
    __shared__ int bc_bin, bc_rank, bc_cnt;

    const int bhc = blockIdx.x, tid = threadIdx.x;
    const int wv = tid >> 6, lane = tid & 63;
    const int bh = bhc >> 6;

    u64 key[32];
    {
        const ulonglong2* p = (const ulonglong2*)(keys + (size_t)bhc * TT + tid * 32);
#pragma unroll
        for (int i = 0; i < 16; i++) { ulonglong2 u = p[i]; key[2*i] = u.x; key[2*i+1] = u.y; }
    }

    u64 thr = 0;
    int need = 128, gshift = 55, prevShift = 0;
    unsigned int* hb = &hist[0][0];

    for (int level = 0; level < 8; level++) {
        const int shift = (level < 7) ? (55 - 8 * level) : 0;
        hb[tid] = 0; hb[tid + 256] = 0; hb[tid + 512] = 0; hb[tid + 768] = 0;
        __syncthreads();
        unsigned int* hw = hist[wv];
        if (level == 0) {
#pragma unroll
            for (int i = 0; i < 32; i++)
                atomicAdd(&hw[(unsigned int)(key[i] >> 55)], 1u);
        } else {
            const u64 pv = thr >> prevShift;
#pragma unroll
            for (int i = 0; i < 32; i++)
                if ((key[i] >> prevShift) == pv)
                    atomicAdd(&hw[(unsigned int)(key[i] >> shift) & 255u], 1u);
        }
        __syncthreads();

        // descending scan: thread tid covers bin 255-tid
        const int b = 255 - tid;
        const int c = hist[0][b] + hist[1][b] + hist[2][b] + hist[3][b];
        int incl = c;
#pragma unroll
        for (int o = 1; o < 64; o <<= 1) {
            const int v = __shfl_up(incl, o);
            if (lane >= o) incl += v;
        }
        if (lane == 63) wsum[wv] = incl;
        __syncthreads();
        int above = incl - c;
        for (int wj = 0; wj < wv; wj++) above += wsum[wj];
        if (above < need && above + c >= need) {
            bc_bin = b; bc_rank = above; bc_cnt = c;
        }
        __syncthreads();
        thr |= ((u64)(unsigned int)bc_bin) << shift;
        need -= bc_rank;
        gshift = shift;
        prevShift = shift;
        if (bc_cnt == need || shift == 0) break;
    }

    // ordered emission + inverse map
    const u64 tg = thr >> gshift;
    int cgt = 0, ceq = 0;
#pragma unroll
    for (int i = 0; i < 32; i++) {
        const u64 kg = key[i] >> gshift;
        cgt += (kg > tg) ? 1 : 0;
        ceq += (kg == tg) ? 1 : 0;
    }
    int ig = cgt, ie = ceq;
#pragma unroll
    for (int o = 1; o < 64; o <<= 1) {
        const int vg = __shfl_up(ig, o);
        const int ve = __shfl_up(ie, o);
        if (lane >= o) { ig += vg; ie += ve; }
    }
    if (lane == 63) { wsum[wv] = ig; wsum[4 + wv] = ie; }
    __syncthreads();
    int pgt = ig - cgt, peq = ie - ceq;
    for (int wj = 0; wj < wv; wj++) { pgt += wsum[wj]; peq += wsum[4 + wj]; }

    const int rneed = need;
    int* outp = indices + bhc * WW;
    unsigned int* cntb = cnt + (bh << 13);
    unsigned short* invb = inv + (((size_t)bh << 13) * INVCAP);
    const int cbase = (bhc & 63) * WW;
    int g = 0, e = 0;
#pragma unroll
    for (int i = 0; i < 32; i++) {
        const int tok = tid * 32 + i;
        const u64 kg = key[i] >> gshift;
        if (kg > tg) {
            const int tb = (peq + e < rneed) ? (peq + e) : rneed;
            const int wpos = pgt + g + tb;
            outp[wpos] = tok;
            const unsigned int pos = atomicAdd(&cntb[tok], 1u);
            if (pos < INVCAP) invb[(size_t)tok * INVCAP + pos] = (unsigned short)(cbase + wpos);
            g++;
        } else if (kg == tg) {
            if (peq + e < rneed) {
                const int wpos = pgt + g + peq + e;
                outp[wpos] = tok;
                const unsigned int pos = atomicAdd(&cntb[tok], 1u);
                if (pos < INVCAP) invb[(size_t)tok * INVCAP + pos] = (unsigned short)(cbase + wpos);
            }
            e++;
        }
    }
}

// ---------------------------------------------------------------------------
// Kernel 3: per-(bh,c) local attention, MFMA bf16. 512 threads = 8 waves.
// LDS 53248 B -> 3 blocks/CU. qs is XOR-swizzled 128x64 (union'd with vt).
// ---------------------------------------------------------------------------
// swizzled address of 8-elem group gi in row: breaks the 128B-row bank aliasing
#define QS_ADDR(row, gi) (((row) << 6) + ((((gi) ^ ((row) & 7))) << 3))

__global__ __launch_bounds__(512) void k_attn(
    const float* __restrict__ qk, const float* __restrict__ vin,
    const float* __restrict__ rel_w, const int* __restrict__ indices,
    float* __restrict__ bo)
{
    __shared__ __attribute__((aligned(16))) __bf16 uv[64 * 136];   // qs (swizzled 128x64) / later v^T
    __shared__ __attribute__((aligned(16))) __bf16 rs[128 * 136];  // R; later P
    __shared__ float invs[128];
    __shared__ int   idxs[128];

    const int tid  = threadIdx.x;
    const int lane = tid & 63;
    const int wv   = tid >> 6;
    const int lo   = lane & 15;
    const int quad = lane >> 4;
    const int rbase = wv * 16;

    const int bhc = blockIdx.x;
    const int bh  = bhc >> 6;
    const int h   = bh & 7;

    if (tid < 128) idxs[tid] = indices[bhc * WW + tid];
    __syncthreads();

    // ---- q gather, v prefetch in regs ----
    const int r  = tid >> 2;          // row 0..127
    const int qp = tid & 3;           // 16-float segment
    const size_t rowoff = ((size_t)bh * TT + idxs[r]) * DD + qp * 16;
    float4 q0, q1, q2, q3, vreg[4];
    {
        const float4* qsrc = (const float4*)(qk + rowoff);
        q0 = qsrc[0]; q1 = qsrc[1]; q2 = qsrc[2]; q3 = qsrc[3];
        const float4* vsrc = (const float4*)(vin + rowoff);
        vreg[0] = vsrc[0]; vreg[1] = vsrc[1]; vreg[2] = vsrc[2]; vreg[3] = vsrc[3];
    }
    {
        float ssq = q0.x*q0.x + q0.y*q0.y + q0.z*q0.z + q0.w*q0.w
                  + q1.x*q1.x + q1.y*q1.y + q1.z*q1.z + q1.w*q1.w
                  + q2.x*q2.x + q2.y*q2.y + q2.z*q2.z + q2.w*q2.w
                  + q3.x*q3.x + q3.y*q3.y + q3.z*q3.z + q3.w*q3.w;
        ssq += __shfl_xor(ssq, 1);
        ssq += __shfl_xor(ssq, 2);
        if (qp == 0) invs[r] = 1.0f / fmaxf(sqrtf(ssq), 1e-12f);
        bf16x8 va, vb;
        va[0]=(__bf16)q0.x; va[1]=(__bf16)q0.y; va[2]=(__bf16)q0.z; va[3]=(__bf16)q0.w;
        va[4]=(__bf16)q1.x; va[5]=(__bf16)q1.y; va[6]=(__bf16)q1.z; va[7]=(__bf16)q1.w;
        vb[0]=(__bf16)q2.x; vb[1]=(__bf16)q2.y; vb[2]=(__bf16)q2.z; vb[3]=(__bf16)q2.w;
        vb[4]=(__bf16)q3.x; vb[5]=(__bf16)q3.y; vb[6]=(__bf16)q3.z; vb[7]=(__bf16)q3.w;
        *(bf16x8*)(uv + QS_ADDR(r, qp * 2))     = va;
        *(bf16x8*)(uv + QS_ADDR(r, qp * 2 + 1)) = vb;
    }
    __syncthreads();

    f32x4 acc[8];

    // ---- R = Q * W^T ----
#pragma unroll
    for (int nt = 0; nt < 8; nt++) acc[nt] = (f32x4){0.f, 0.f, 0.f, 0.f};
#pragma unroll
    for (int k0 = 0; k0 < 64; k0 += 32) {
        bf16x8 qa = *(const bf16x8*)(uv + QS_ADDR(rbase + lo, (k0 >> 3) + quad));
#pragma unroll
        for (int nt = 0; nt < 8; nt++) {
            const float* wp = rel_w + (size_t)((nt * 16 + lo) * 8 + h) * 64 + k0 + quad * 8;
            float4 w0 = ((const float4*)wp)[0];
            float4 w1 = ((const float4*)wp)[1];
            bf16x8 wb;
            wb[0]=(__bf16)w0.x; wb[1]=(__bf16)w0.y; wb[2]=(__bf16)w0.z; wb[3]=(__bf16)w0.w;
            wb[4]=(__bf16)w1.x; wb[5]=(__bf16)w1.y; wb[6]=(__bf16)w1.z; wb[7]=(__bf16)w1.w;
            acc[nt] = MFMA(qa, wb, acc[nt]);
        }
    }
#pragma unroll
    for (int nt = 0; nt < 8; nt++)
#pragma unroll
        for (int rg = 0; rg < 4; rg++)
            rs[(rbase + quad * 4 + rg) * 136 + nt * 16 + lo] = (__bf16)acc[nt][rg];

    // ---- dots = (Q*Q^T) * inv_j * scale ----
#pragma unroll
    for (int nt = 0; nt < 8; nt++) acc[nt] = (f32x4){0.f, 0.f, 0.f, 0.f};
#pragma unroll
    for (int k0 = 0; k0 < 64; k0 += 32) {
        bf16x8 qa = *(const bf16x8*)(uv + QS_ADDR(rbase + lo, (k0 >> 3) + quad));
#pragma unroll
        for (int nt = 0; nt < 8; nt++) {
            bf16x8 qb = *(const bf16x8*)(uv + QS_ADDR(nt * 16 + lo, (k0 >> 3) + quad));
            acc[nt] = MFMA(qa, qb, acc[nt]);
        }
    }

    float inv_j[8];
#pragma unroll
    for (int nt = 0; nt < 8; nt++) inv_j[nt] = invs[nt * 16 + lo];

    // bias (shifted rel) + self-mask
#pragma unroll
    for (int rg = 0; rg < 4; rg++) {
        const int i = rbase + quad * 4 + rg;
#pragma unroll
        for (int nt = 0; nt < 8; nt++) {
            const int j = nt * 16 + lo;
            float val = acc[nt][rg] * inv_j[nt] * SCALE;
            if (j <= i) val += SCALE * (float)rs[i * 136 + (j + 127 - i)];
            if (j == i) val = -50000.0f;
            acc[nt][rg] = val;
        }
    }

    // row softmax
#pragma unroll
    for (int rg = 0; rg < 4; rg++) {
        float m = -3.0e38f;
#pragma unroll
        for (int nt = 0; nt < 8; nt++) m = fmaxf(m, acc[nt][rg]);
#pragma unroll
        for (int msk = 1; msk < 16; msk <<= 1) m = fmaxf(m, __shfl_xor(m, msk));
        float s = 0.f;
#pragma unroll
        for (int nt = 0; nt < 8; nt++) {
            const float e = __expf(acc[nt][rg] - m);
            acc[nt][rg] = e; s += e;
        }
#pragma unroll
        for (int msk = 1; msk < 16; msk <<= 1) s += __shfl_xor(s, msk);
        const float is = 1.0f / s;
        const int i = rbase + quad * 4 + rg;
#pragma unroll
        for (int nt = 0; nt < 8; nt++)
            rs[i * 136 + nt * 16 + lo] = (__bf16)(acc[nt][rg] * is);
    }
    __syncthreads();   // all reads of uv(q) done; P complete

    // ---- v (from regs) transposed into uv: vt[d][j], stride 136 ----
    __bf16* vt = uv;
#pragma unroll
    for (int i = 0; i < 4; i++) {
        vt[(qp * 16 + 4*i + 0) * 136 + r] = (__bf16)vreg[i].x;
        vt[(qp * 16 + 4*i + 1) * 136 + r] = (__bf16)vreg[i].y;
        vt[(qp * 16 + 4*i + 2) * 136 + r] = (__bf16)vreg[i].z;
        vt[(qp * 16 + 4*i + 3) * 136 + r] = (__bf16)vreg[i].w;
    }
    __syncthreads();

    // ---- bo = P * V ----
    f32x4 accO[4];
#pragma unroll
    for (int nt = 0; nt < 4; nt++) accO[nt] = (f32x4){0.f, 0.f, 0.f, 0.f};
#pragma unroll
    for (int k0 = 0; k0 < 128; k0 += 32) {
        bf16x8 pa = *(const bf16x8*)(rs + (rbase + lo) * 136 + k0 + quad * 8);
#pragma unroll
        for (int nt = 0; nt < 4; nt++) {
            bf16x8 vb = *(const bf16x8*)(vt + (nt * 16 + lo) * 136 + k0 + quad * 8);
            accO[nt] = MFMA(pa, vb, accO[nt]);
        }
    }

    // ---- dense store ----
    float* bb = bo + (size_t)bhc * (WW * DD);
#pragma unroll
    for (int rg = 0; rg < 4; rg++) {
        const int i = rbase + quad * 4 + rg;
#pragma unroll
        for (int nt = 0; nt < 4; nt++)
            bb[(size_t)i * DD + nt * 16 + lo] = accO[nt][rg];
    }
}

// ---------------------------------------------------------------------------
// Kernel 4: per-token gather-sum of dense bo rows + normalize (+ loss)
// ---------------------------------------------------------------------------
__global__ __launch_bounds__(256) void k_out(
    const float* __restrict__ bo, const unsigned int* __restrict__ cnt,
    const unsigned short* __restrict__ inv, const double* __restrict__ lossa,
    float* __restrict__ out)
{
    const int tid = threadIdx.x;
    const int g = blockIdx.x * 16 + (tid >> 4);      // global token 0..262143
    const int l = tid & 15;
    const int bh = g >> 13;
    const unsigned int n = cnt[g];
    const int nc = (n < (unsigned)INVCAP) ? (int)n : INVCAP;
    const unsigned short* ip = inv + (size_t)g * INVCAP;
    const float* bbase = bo + (((size_t)bh << 13) * DD);
    float4 s = {0.f, 0.f, 0.f, 0.f};
    for (int e = 0; e < nc; e++) {
        const int slot = ip[e];
        float4 v4 = *(const float4*)(bbase + (size_t)slot * DD + l * 4);
        s.x += v4.x; s.y += v4.y; s.z += v4.z; s.w += v4.w;
    }
    const float r = 1.0f / ((float)n + 1e-5f);
    s.x *= r; s.y *= r; s.z *= r; s.w *= r;
    *(float4*)(out + (size_t)g * DD + l * 4) = s;
    if (g == 0 && l == 0) out[16777216] = (float)(lossa[0] * (0.0001 / 16777216.0));
}

// ---------------------------------------------------------------------------
extern "C" void kernel_launch(void* const* d_in, const int* in_sizes, int n_in,
                              void* d_out, int out_size, void* d_ws, size_t ws_size,
                              hipStream_t stream) {
    (void)in_sizes; (void)n_in; (void)ws_size; (void)out_size;
    const float* qk    = (const float*)d_in[0];
    const float* v     = (const float*)d_in[1];
    const float* means = (const float*)d_in[2];
    const float* rel_w = (const float*)d_in[3];
    float* out = (float*)d_out;

    // ws layout:
    //   [keys u64 134MB]          (bo 67MB aliases front half after k_topk)
    //   [idx 1MB]
    //   [cnt 1MB][lossa pad 4KB]  (memset region)
    //   [inv u16 cap24 12.6MB]
    char* ws = (char*)d_ws;
    const size_t KEYS_B = (size_t)BHN * NC * TT * 8;        // 134217728
    const size_t IDX_B  = (size_t)BHN * NC * WW * 4;        // 1048576
    const size_t CNT_B  = (size_t)BHN * TT * 4;             // 1048576
    u64*            keys  = (u64*)ws;
    float*          bo    = (float*)ws;                     // alias, post-k_topk
    int*            idx   = (int*)(ws + KEYS_B);
    unsigned int*   cnt   = (unsigned int*)(ws + KEYS_B + IDX_B);
    double*         lossa = (double*)(ws + KEYS_B + IDX_B + CNT_B);
    unsigned short* inv   = (unsigned short*)(ws + KEYS_B + IDX_B + CNT_B + 4096);

    hipMemsetAsync(ws + KEYS_B + IDX_B, 0, CNT_B + 4096, stream);

    k_dists<<<dim3(BHN, TT / 512), 256, 0, stream>>>(qk, means, keys, lossa);
    k_topk<<<BHN * NC, 256, 0, stream>>>(keys, idx, cnt, inv);
    k_attn<<<BHN * NC, 512, 0, stream>>>(qk, v, rel_w, idx, bo);
    k_out<<<BHN * TT / 16, 256, 0, stream>>>(bo, cnt, inv, lossa, out);
}

// Round 5
// 387.981 us; speedup vs baseline: 1.2981x; 1.2981x over previous
//
#include <hip/hip_runtime.h>
#include <hip/hip_bf16.h>
#include <math.h>

// Problem constants (b=4,h=8,t=8192,d=64, c=64 clusters, wsz=128)
#define NB 4
#define NH 8
#define TT 8192
#define DD 64
#define NC 64
#define WW 128
#define BHN 32            // NB*NH
#define SCALE 0.125f      // d^-0.5
#define INVCAP 24         // max tracked clusters per token
#define TPB 128           // tokens per k_dists block

typedef __bf16  bf16x8 __attribute__((ext_vector_type(8)));
typedef float   f32x4  __attribute__((ext_vector_type(4)));
typedef double  f64x4  __attribute__((ext_vector_type(4)));
typedef unsigned long long u64;

#define MFMA(a, b, c) __builtin_amdgcn_mfma_f32_16x16x32_bf16((a), (b), (c), 0, 0, 0)

// monotone fixed-point key: dv in [-1,1] -> (dv+1)*2^62, clamped to [0, <2^63)
__device__ __forceinline__ u64 fixkey(double dv) {
    double k = (dv + 1.0) * 4611686018427387904.0;
    k = fmin(fmax(k, 0.0), 9223371487098961920.0);
    return (u64)k;
}

// ---------------------------------------------------------------------------
// Kernel 1: routing dists via fp64 MFMA -> fixed-point u64 keys (+ loss).
// Block: 128 tokens x 64 clusters. Wave w: token-tiles {2w,2w+1} x 4 c-tiles.
// v_mfma_f64_16x16x4: A[m=cluster][k], B[k][n=token], D col=token row=cluster.
// ---------------------------------------------------------------------------
__global__ __launch_bounds__(256) void k_dists(
    const float* __restrict__ qk, const float* __restrict__ means,
    u64* __restrict__ keys, double* __restrict__ lossa)
{
    __shared__ float  qS[TPB * 66];      // 33792 B
    __shared__ float  mS[NC * 65];       // 16640 B
    __shared__ double invS[TPB];         // 1024 B
    __shared__ double s2S[TPB];          // 1024 B (ss*inv^2)
    __shared__ double mn2[NC];           // 512 B
    __shared__ double red[4];

    const int bh  = blockIdx.x;          // 0..31
    const int h   = bh & 7;
    const int tid = threadIdx.x;
    const int t0  = blockIdx.y * TPB;

    // stage means (fp32, stride 65)
    {
        const float* mp = means + h * (NC * DD);
        for (int i = tid; i < NC * DD; i += 256)
            mS[(i >> 6) * 65 + (i & 63)] = mp[i];
    }
    // stage qk rows (fp32, stride 66), coalesced float4 reads
    {
        const float4* src = (const float4*)(qk + ((size_t)bh * TT + t0) * DD);
        for (int i = tid; i < TPB * DD / 4; i += 256) {
            const float4 v = src[i];
            float* dst = qS + (i >> 4) * 66 + (i & 15) * 4;
            *(float2*)(dst)     = make_float2(v.x, v.y);
            *(float2*)(dst + 2) = make_float2(v.z, v.w);
        }
    }
    __syncthreads();

    // means norms^2 (fp64)
    if (tid < NC) {
        double s = 0.0;
        const float* rp = mS + tid * 65;
        for (int d = 0; d < DD; d++) { const double m = (double)rp[d]; s = fma(m, m, s); }
        mn2[tid] = s;
    }
    // token norms (fp64)
    if (tid < TPB) {
        double s = 0.0;
        const float* rp = qS + tid * 66;
#pragma unroll
        for (int d = 0; d < DD; d += 2) {
            const float2 f = *(const float2*)(rp + d);
            s = fma((double)f.x, (double)f.x, s);
            s = fma((double)f.y, (double)f.y, s);
        }
        const double inv = 1.0 / fmax(sqrt(s), 1e-12);
        invS[tid] = inv;
        s2S[tid]  = s * inv * inv;
    }
    __syncthreads();

    const int lane = tid & 63;
    const int wv   = tid >> 6;
    const int lo   = lane & 15;
    const int quad = lane >> 4;

    double lt_lane = 0.0;

#pragma unroll
    for (int tt = 0; tt < 2; tt++) {
        const int tloc = (wv * 2 + tt) * 16 + lo;     // local token for this lane-col
        // B fragments (tokens), cached fp64: B[k = quad+4*step][n = lo]
        double Bf[16];
#pragma unroll
        for (int s = 0; s < 16; s++)
            Bf[s] = (double)qS[tloc * 66 + quad + 4 * s];
        const double inv = invS[tloc];

        double rawmax = -1.0e300; int cbest = 0;
        u64* kout = keys + (size_t)bh * NC * TT + (t0 + tloc);

#pragma unroll
        for (int ct = 0; ct < 4; ct++) {
            f64x4 acc = (f64x4){0.0, 0.0, 0.0, 0.0};
#pragma unroll
            for (int s = 0; s < 16; s++) {
                const double Af = (double)mS[(ct * 16 + lo) * 65 + quad + 4 * s];
                acc = __builtin_amdgcn_mfma_f64_16x16x4f64(Af, Bf[s], acc, 0, 0, 0);
            }
#pragma unroll
            for (int r = 0; r < 4; r++) {
                const double raw = acc[r];
                const int c = ct * 16 + quad * 4 + r;
                if (raw > rawmax) { rawmax = raw; cbest = c; }
                kout[(size_t)c * TT] = fixkey(raw * inv);
            }
        }

        // merge argmax across quads (lanes lo+16q share token lo)
#pragma unroll
        for (int off = 16; off < 64; off <<= 1) {
            const double ov = __shfl_xor(rawmax, off);
            const int    oc = __shfl_xor(cbest, off);
            if (ov > rawmax || (ov == rawmax && oc < cbest)) { rawmax = ov; cbest = oc; }
        }
        if (quad == 0)
            lt_lane += s2S[tloc] + mn2[cbest] - 2.0 * rawmax * inv;
    }

    // block loss reduction
#pragma unroll
    for (int o = 32; o; o >>= 1) lt_lane += __shfl_xor(lt_lane, o);
    if (lane == 0) red[wv] = lt_lane;
    __syncthreads();
    if (tid == 0) atomicAdd(lossa, red[0] + red[1] + red[2] + red[3]);
}

// ---------------------------------------------------------------------------
// Kernel 2: top-128 per (bh,c), 8-bit radix select on fixed-point keys.
// ---------------------------------------------------------------------------
__global__ __launch_bounds__(256) void k_topk(
    const u64* __restrict__ keys, int* __restrict__ indices,
    unsigned int* __restrict__ cnt, unsigned short* __restrict__ inv)
{
    __shared__ unsigned int hist[4][256];    // 4 KB
    __shared__ int wsum[8];
    __shared__ int bc_bin, bc_rank, bc_cnt;

    const int bhc = blockIdx.x, tid = threadIdx.x;
    const int wv = tid >> 6, lane = tid & 63;
    const int bh = bhc >> 6;

    u64 key[32];
    {
        const ulonglong2* p = (const ulonglong2*)(keys + (size_t)bhc * TT + tid * 32);
#pragma unroll
        for (int i = 0; i < 16; i++) { ulonglong2 u = p[i]; key[2*i] = u.x; key[2*i+1] = u.y; }
    }

    u64 thr = 0;
    int need = 128, gshift = 55, prevShift = 0;
    unsigned int* hb = &hist[0][0];

    for (int level = 0; level < 8; level++) {
        const int shift = (level < 7) ? (55 - 8 * level) : 0;
        hb[tid] = 0; hb[tid + 256] = 0; hb[tid + 512] = 0; hb[tid + 768] = 0;
        __syncthreads();
        unsigned int* hw = hist[wv];
        if (level == 0) {
#pragma unroll
            for (int i = 0; i < 32; i++)
                atomicAdd(&hw[(unsigned int)(key[i] >> 55)], 1u);
        } else {
            const u64 pv = thr >> prevShift;
#pragma unroll
            for (int i = 0; i < 32; i++)
                if ((key[i] >> prevShift) == pv)
                    atomicAdd(&hw[(unsigned int)(key[i] >> shift) & 255u], 1u);
        }
        __syncthreads();

        const int b = 255 - tid;
        const int c = hist[0][b] + hist[1][b] + hist[2][b] + hist[3][b];
        int incl = c;
#pragma unroll
        for (int o = 1; o < 64; o <<= 1) {
            const int v = __shfl_up(incl, o);
            if (lane >= o) incl += v;
        }
        if (lane == 63) wsum[wv] = incl;
        __syncthreads();
        int above = incl - c;
        for (int wj = 0; wj < wv; wj++) above += wsum[wj];
        if (above < need && above + c >= need) {
            bc_bin = b; bc_rank = above; bc_cnt = c;
        }
        __syncthreads();
        thr |= ((u64)(unsigned int)bc_bin) << shift;
        need -= bc_rank;
        gshift = shift;
        prevShift = shift;
        if (bc_cnt == need || shift == 0) break;
    }

    // ordered emission + inverse map
    const u64 tg = thr >> gshift;
    int cgt = 0, ceq = 0;
#pragma unroll
    for (int i = 0; i < 32; i++) {
        const u64 kg = key[i] >> gshift;
        cgt += (kg > tg) ? 1 : 0;
        ceq += (kg == tg) ? 1 : 0;
    }
    int ig = cgt, ie = ceq;
#pragma unroll
    for (int o = 1; o < 64; o <<= 1) {
        const int vg = __shfl_up(ig, o);
        const int ve = __shfl_up(ie, o);
        if (lane >= o) { ig += vg; ie += ve; }
    }
    if (lane == 63) { wsum[wv] = ig; wsum[4 + wv] = ie; }
    __syncthreads();
    int pgt = ig - cgt, peq = ie - ceq;
    for (int wj = 0; wj < wv; wj++) { pgt += wsum[wj]; peq += wsum[4 + wj]; }

    const int rneed = need;
    int* outp = indices + bhc * WW;
    unsigned int* cntb = cnt + (bh << 13);
    unsigned short* invb = inv + (((size_t)bh << 13) * INVCAP);
    const int cbase = (bhc & 63) * WW;
    int g = 0, e = 0;
#pragma unroll
    for (int i = 0; i < 32; i++) {
        const int tok = tid * 32 + i;
        const u64 kg = key[i] >> gshift;
        if (kg > tg) {
            const int tb = (peq + e < rneed) ? (peq + e) : rneed;
            const int wpos = pgt + g + tb;
            outp[wpos] = tok;
            const unsigned int pos = atomicAdd(&cntb[tok], 1u);
            if (pos < INVCAP) invb[(size_t)tok * INVCAP + pos] = (unsigned short)(cbase + wpos);
            g++;
        } else if (kg == tg) {
            if (peq + e < rneed) {
                const int wpos = pgt + g + peq + e;
                outp[wpos] = tok;
                const unsigned int pos = atomicAdd(&cntb[tok], 1u);
                if (pos < INVCAP) invb[(size_t)tok * INVCAP + pos] = (unsigned short)(cbase + wpos);
            }
            e++;
        }
    }
}

// ---------------------------------------------------------------------------
// Kernel 3: per-(bh,c) local attention, MFMA bf16. 512 threads = 8 waves.
// LDS 53248 B -> 3 blocks/CU. qs XOR-swizzled 128x64 (union'd with vt).
// ---------------------------------------------------------------------------
#define QS_ADDR(row, gi) (((row) << 6) + ((((gi) ^ ((row) & 7))) << 3))

__global__ __launch_bounds__(512) void k_attn(
    const float* __restrict__ qk, const float* __restrict__ vin,
    const float* __restrict__ rel_w, const int* __restrict__ indices,
    float* __restrict__ bo)
{
    __shared__ __attribute__((aligned(16))) __bf16 uv[64 * 136];   // qs / later v^T
    __shared__ __attribute__((aligned(16))) __bf16 rs[128 * 136];  // R; later P
    __shared__ float invs[128];
    __shared__ int   idxs[128];

    const int tid  = threadIdx.x;
    const int lane = tid & 63;
    const int wv   = tid >> 6;
    const int lo   = lane & 15;
    const int quad = lane >> 4;
    const int rbase = wv * 16;

    const int bhc = blockIdx.x;
    const int bh  = bhc >> 6;
    const int h   = bh & 7;

    if (tid < 128) idxs[tid] = indices[bhc * WW + tid];
    __syncthreads();

    // ---- q gather, v prefetch in regs ----
    const int r  = tid >> 2;          // row 0..127
    const int qp = tid & 3;           // 16-float segment
    const size_t rowoff = ((size_t)bh * TT + idxs[r]) * DD + qp * 16;
    float4 q0, q1, q2, q3, vreg[4];
    {
        const float4* qsrc = (const float4*)(qk + rowoff);
        q0 = qsrc[0]; q1 = qsrc[1]; q2 = qsrc[2]; q3 = qsrc[3];
        const float4* vsrc = (const float4*)(vin + rowoff);
        vreg[0] = vsrc[0]; vreg[1] = vsrc[1]; vreg[2] = vsrc[2]; vreg[3] = vsrc[3];
    }
    {
        float ssq = q0.x*q0.x + q0.y*q0.y + q0.z*q0.z + q0.w*q0.w
                  + q1.x*q1.x + q1.y*q1.y + q1.z*q1.z + q1.w*q1.w
                  + q2.x*q2.x + q2.y*q2.y + q2.z*q2.z + q2.w*q2.w
                  + q3.x*q3.x + q3.y*q3.y + q3.z*q3.z + q3.w*q3.w;
        ssq += __shfl_xor(ssq, 1);
        ssq += __shfl_xor(ssq, 2);
        if (qp == 0) invs[r] = 1.0f / fmaxf(sqrtf(ssq), 1e-12f);
        bf16x8 va, vb;
        va[0]=(__bf16)q0.x; va[1]=(__bf16)q0.y; va[2]=(__bf16)q0.z; va[3]=(__bf16)q0.w;
        va[4]=(__bf16)q1.x; va[5]=(__bf16)q1.y; va[6]=(__bf16)q1.z; va[7]=(__bf16)q1.w;
        vb[0]=(__bf16)q2.x; vb[1]=(__bf16)q2.y; vb[2]=(__bf16)q2.z; vb[3]=(__bf16)q2.w;
        vb[4]=(__bf16)q3.x; vb[5]=(__bf16)q3.y; vb[6]=(__bf16)q3.z; vb[7]=(__bf16)q3.w;
        *(bf16x8*)(uv + QS_ADDR(r, qp * 2))     = va;
        *(bf16x8*)(uv + QS_ADDR(r, qp * 2 + 1)) = vb;
    }
    __syncthreads();

    f32x4 acc[8];

    // ---- R = Q * W^T ----
#pragma unroll
    for (int nt = 0; nt < 8; nt++) acc[nt] = (f32x4){0.f, 0.f, 0.f, 0.f};
#pragma unroll
    for (int k0 = 0; k0 < 64; k0 += 32) {
        bf16x8 qa = *(const bf16x8*)(uv + QS_ADDR(rbase + lo, (k0 >> 3) + quad));
#pragma unroll
        for (int nt = 0; nt < 8; nt++) {
            const float* wp = rel_w + (size_t)((nt * 16 + lo) * 8 + h) * 64 + k0 + quad * 8;
            float4 w0 = ((const float4*)wp)[0];
            float4 w1 = ((const float4*)wp)[1];
            bf16x8 wb;
            wb[0]=(__bf16)w0.x; wb[1]=(__bf16)w0.y; wb[2]=(__bf16)w0.z; wb[3]=(__bf16)w0.w;
            wb[4]=(__bf16)w1.x; wb[5]=(__bf16)w1.y; wb[6]=(__bf16)w1.z; wb[7]=(__bf16)w1.w;
            acc[nt] = MFMA(qa, wb, acc[nt]);
        }
    }
#pragma unroll
    for (int nt = 0; nt < 8; nt++)
#pragma unroll
        for (int rg = 0; rg < 4; rg++)
            rs[(rbase + quad * 4 + rg) * 136 + nt * 16 + lo] = (__bf16)acc[nt][rg];

    // ---- dots = (Q*Q^T) * inv_j * scale ----
#pragma unroll
    for (int nt = 0; nt < 8; nt++) acc[nt] = (f32x4){0.f, 0.f, 0.f, 0.f};
#pragma unroll
    for (int k0 = 0; k0 < 64; k0 += 32) {
        bf16x8 qa = *(const bf16x8*)(uv + QS_ADDR(rbase + lo, (k0 >> 3) + quad));
#pragma unroll
        for (int nt = 0; nt < 8; nt++) {
            bf16x8 qb = *(const bf16x8*)(uv + QS_ADDR(nt * 16 + lo, (k0 >> 3) + quad));
            acc[nt] = MFMA(qa, qb, acc[nt]);
        }
    }

    float inv_j[8];
#pragma unroll
    for (int nt = 0; nt < 8; nt++) inv_j[nt] = invs[nt * 16 + lo];

    // bias (shifted rel) + self-mask
#pragma unroll
    for (int rg = 0; rg < 4; rg++) {
        const int i = rbase + quad * 4 + rg;
#pragma unroll
        for (int nt = 0; nt < 8; nt++) {
            const int j = nt * 16 + lo;
            float val = acc[nt][rg] * inv_j[nt] * SCALE;
            if (j <= i) val += SCALE * (float)rs[i * 136 + (j + 127 - i)];
            if (j == i) val = -50000.0f;
            acc[nt][rg] = val;
        }
    }

    // row softmax
#pragma unroll
    for (int rg = 0; rg < 4; rg++) {
        float m = -3.0e38f;
#pragma unroll
        for (int nt = 0; nt < 8; nt++) m = fmaxf(m, acc[nt][rg]);
#pragma unroll
        for (int msk = 1; msk < 16; msk <<= 1) m = fmaxf(m, __shfl_xor(m, msk));
        float s = 0.f;
#pragma unroll
        for (int nt = 0; nt < 8; nt++) {
            const float e = __expf(acc[nt][rg] - m);
            acc[nt][rg] = e; s += e;
        }
#pragma unroll
        for (int msk = 1; msk < 16; msk <<= 1) s += __shfl_xor(s, msk);
        const float is = 1.0f / s;
        const int i = rbase + quad * 4 + rg;
#pragma unroll
        for (int nt = 0; nt < 8; nt++)
            rs[i * 136 + nt * 16 + lo] = (__bf16)(acc[nt][rg] * is);
    }
    __syncthreads();   // all reads of uv(q) done; P complete

    // ---- v (from regs) transposed into uv: vt[d][j], stride 136 ----
    __bf16* vt = uv;
#pragma unroll
    for (int i = 0; i < 4; i++) {
        vt[(qp * 16 + 4*i + 0) * 136 + r] = (__bf16)vreg[i].x;
        vt[(qp * 16 + 4*i + 1) * 136 + r] = (__bf16)vreg[i].y;
        vt[(qp * 16 + 4*i + 2) * 136 + r] = (__bf16)vreg[i].z;
        vt[(qp * 16 + 4*i + 3) * 136 + r] = (__bf16)vreg[i].w;
    }
    __syncthreads();

    // ---- bo = P * V ----
    f32x4 accO[4];
#pragma unroll
    for (int nt = 0; nt < 4; nt++) accO[nt] = (f32x4){0.f, 0.f, 0.f, 0.f};
#pragma unroll
    for (int k0 = 0; k0 < 128; k0 += 32) {
        bf16x8 pa = *(const bf16x8*)(rs + (rbase + lo) * 136 + k0 + quad * 8);
#pragma unroll
        for (int nt = 0; nt < 4; nt++) {
            bf16x8 vb = *(const bf16x8*)(vt + (nt * 16 + lo) * 136 + k0 + quad * 8);
            accO[nt] = MFMA(pa, vb, accO[nt]);
        }
    }

    // ---- dense store ----
    float* bb = bo + (size_t)bhc * (WW * DD);
#pragma unroll
    for (int rg = 0; rg < 4; rg++) {
        const int i = rbase + quad * 4 + rg;
#pragma unroll
        for (int nt = 0; nt < 4; nt++)
            bb[(size_t)i * DD + nt * 16 + lo] = accO[nt][rg];
    }
}

// ---------------------------------------------------------------------------
// Kernel 4: per-token gather-sum of dense bo rows + normalize (+ loss)
// ---------------------------------------------------------------------------
__global__ __launch_bounds__(256) void k_out(
    const float* __restrict__ bo, const unsigned int* __restrict__ cnt,
    const unsigned short* __restrict__ inv, const double* __restrict__ lossa,
    float* __restrict__ out)
{
    const int tid = threadIdx.x;
    const int g = blockIdx.x * 16 + (tid >> 4);      // global token 0..262143
    const int l = tid & 15;
    const int bh = g >> 13;
    const unsigned int n = cnt[g];
    const int nc = (n < (unsigned)INVCAP) ? (int)n : INVCAP;
    const unsigned short* ip = inv + (size_t)g * INVCAP;
    const float* bbase = bo + (((size_t)bh << 13) * DD);
    float4 s = {0.f, 0.f, 0.f, 0.f};
    for (int e = 0; e < nc; e++) {
        const int slot = ip[e];
        float4 v4 = *(const float4*)(bbase + (size_t)slot * DD + l * 4);
        s.x += v4.x; s.y += v4.y; s.z += v4.z; s.w += v4.w;
    }
    const float r = 1.0f / ((float)n + 1e-5f);
    s.x *= r; s.y *= r; s.z *= r; s.w *= r;
    *(float4*)(out + (size_t)g * DD + l * 4) = s;
    if (g == 0 && l == 0) out[16777216] = (float)(lossa[0] * (0.0001 / 16777216.0));
}

// ---------------------------------------------------------------------------
extern "C" void kernel_launch(void* const* d_in, const int* in_sizes, int n_in,
                              void* d_out, int out_size, void* d_ws, size_t ws_size,
                              hipStream_t stream) {
    (void)in_sizes; (void)n_in; (void)ws_size; (void)out_size;
    const float* qk    = (const float*)d_in[0];
    const float* v     = (const float*)d_in[1];
    const float* means = (const float*)d_in[2];
    const float* rel_w = (const float*)d_in[3];
    float* out = (float*)d_out;

    // ws layout:
    //   [keys u64 134MB]          (bo 67MB aliases front half after k_topk)
    //   [idx 1MB]
    //   [cnt 1MB][lossa pad 4KB]  (memset region)
    //   [inv u16 cap24 12.6MB]
    char* ws = (char*)d_ws;
    const size_t KEYS_B = (size_t)BHN * NC * TT * 8;        // 134217728
    const size_t IDX_B  = (size_t)BHN * NC * WW * 4;        // 1048576
    const size_t CNT_B  = (size_t)BHN * TT * 4;             // 1048576
    u64*            keys  = (u64*)ws;
    float*          bo    = (float*)ws;                     // alias, post-k_topk
    int*            idx   = (int*)(ws + KEYS_B);
    unsigned int*   cnt   = (unsigned int*)(ws + KEYS_B + IDX_B);
    double*         lossa = (double*)(ws + KEYS_B + IDX_B + CNT_B);
    unsigned short* inv   = (unsigned short*)(ws + KEYS_B + IDX_B + CNT_B + 4096);

    hipMemsetAsync(ws + KEYS_B + IDX_B, 0, CNT_B + 4096, stream);

    k_dists<<<dim3(BHN, TT / TPB), 256, 0, stream>>>(qk, means, keys, lossa);
    k_topk<<<BHN * NC, 256, 0, stream>>>(keys, idx, cnt, inv);
    k_attn<<<BHN * NC, 512, 0, stream>>>(qk, v, rel_w, idx, bo);
    k_out<<<BHN * TT / 16, 256, 0, stream>>>(bo, cnt, inv, lossa, out);
}